// Round 4
// baseline (299.901 us; speedup 1.0000x reference)
//
#include <hip/hip_runtime.h>
#include <stdint.h>

// FFN: x[16384,1024] -> relu(x@W1^T+b1)[16384,4096] -> q_e4m3 -> @W2^T+b2 -> q_e5m10
// Round 6: barrier-light K-loop (AITER-style). Round-5 post-mortem showed the
// 8-barriers/tile schedule serializes LDS and MFMA block-wide into alternating
// windows (model: 2480 MFMA + 2300 LDS = 4780 ~= measured 4610 cyc/tile).
// Mid/end-phase barriers protect nothing intra-tile (reads can't race reads);
// the only required sync is at the tile boundary: drain own stages (vmcnt) +
// one s_barrier. New structure per tile:
//   [issue all 8 gl_lds stages for t+1 into buf^1]   <- oldest-possible issue
//   4 x { ds_read quadrant (+B at p0), setprio(1), 16 MFMA, setprio(0) }
//   s_waitcnt vmcnt(0)   <- drains loads ~2500cy old: ~free (not a young-drain)
//   s_barrier
// Waves desync within the tile -> MFMA overlaps ds_read across waves; target
// per-tile ~= max(MFMA 2480, LDS ~2800) + barrier ~= 3000 cyc.
// Epilogue (round 4) unchanged: division-free e4m3 + swizzled LDS transpose.

#define M_TOT 16384
#define D_DIM 1024
#define H_DIM 4096

typedef _Float16 f16x8 __attribute__((ext_vector_type(8)));
typedef _Float16 f16x4 __attribute__((ext_vector_type(4)));
typedef float f32x4 __attribute__((ext_vector_type(4)));

// global -> LDS direct copy, 16B per lane. LDS dest = wave-uniform base + lane*16.
__device__ __forceinline__ void gl16(const void* g, void* l) {
    __builtin_amdgcn_global_load_lds(
        (const __attribute__((address_space(1))) unsigned int*)(uintptr_t)g,
        (__attribute__((address_space(3))) unsigned int*)(unsigned int)(uintptr_t)l,
        16, 0, 0);
}

// e4m3 quantize (reference float_quantize exp=4 man=3: bias=7, min normal exp -6,
// subnormal quantum 2^-9, RNE, overflow->inf unreachable here: |x| << 240).
__device__ __forceinline__ float q_e4m3_any(float x) {
    uint32_t t = __float_as_uint(x);
    uint32_t s = t & 0x80000000u;
    uint32_t m = t & 0x7fffffffu;
    uint32_t tn = (m + 0x7ffffu + ((m >> 20) & 1u)) & 0xfff00000u;
    float qn = __uint_as_float(tn | s);
    float qs = rintf(x * 512.0f) * 0.001953125f;   // RNE, exact scales
    return __uint_as_float(m) < 0.015625f ? qs : qn;
}

// positive-input fast path (post-relu): no sign handling
__device__ __forceinline__ _Float16 q_e4m3_pos(float v) {
    uint32_t t = __float_as_uint(v);
    uint32_t tn = (t + 0x7ffffu + ((t >> 20) & 1u)) & 0xfff00000u;
    float qn = __uint_as_float(tn);
    float qs = rintf(v * 512.0f) * 0.001953125f;
    return (_Float16)(v < 0.015625f ? qs : qn);
}

// ---- pre-pass: fp32 -> f16 (RNE), vectorized x4 ----
__global__ __launch_bounds__(256) void cvt_f16_kernel(
    const float* __restrict__ in, _Float16* __restrict__ out, int n4)
{
    int i = blockIdx.x * 256 + threadIdx.x;
    if (i >= n4) return;
    float4 v = reinterpret_cast<const float4*>(in)[i];
    f16x4 hv = {(_Float16)v.x, (_Float16)v.y, (_Float16)v.z, (_Float16)v.w};
    reinterpret_cast<f16x4*>(out)[i] = hv;
}

// ---- pre-pass: fp32 -> e4m3 value stored as f16 (exactly representable) ----
__global__ __launch_bounds__(256) void quant_e4m3_kernel(
    const float* __restrict__ in, _Float16* __restrict__ outq, int n4)
{
    int i = blockIdx.x * 256 + threadIdx.x;
    if (i >= n4) return;
    float4 v = reinterpret_cast<const float4*>(in)[i];
    f16x4 q = {(_Float16)q_e4m3_any(v.x), (_Float16)q_e4m3_any(v.y),
               (_Float16)q_e4m3_any(v.z), (_Float16)q_e4m3_any(v.w)};
    reinterpret_cast<f16x4*>(outq)[i] = q;
}

// ---- unified 256x256 GEMM, NT (A[M,K], B[N,K] row-major), f16 MFMA fp32 acc ----
// G1=true : epilogue = +bias, relu, q_e4m3, LDS-transpose, coalesced f16 store
// G1=false: epilogue = +f16(bias), f16-roundtrip, store fp32 (already coalesced)
template<int K, int N, bool G1>
__global__ __launch_bounds__(512) void gemm_ffn(
    const _Float16* __restrict__ A, const _Float16* __restrict__ B,
    const float* __restrict__ bias, void* __restrict__ Cv)
{
    // 2 dbuf x [256 rows][64 K] f16 each for A and B: 128 KiB total.
    // Single array so the epilogue can reuse all 128 KiB as the C tile.
    __shared__ __align__(16) _Float16 smem[65536];
    _Float16* sA = smem;            // 2 x 16384
    _Float16* sB = smem + 32768;    // 2 x 16384

    const int tid  = threadIdx.x;
    const int lane = tid & 63;
    const int w    = tid >> 6;            // 8 waves: 2(M) x 4(N)
    const int wr   = w >> 2, wc = w & 3;  // per-wave C: 128 rows x 64 cols
    const int fr   = lane & 15, kq = lane >> 4;

    // T1: bijective XCD-chunked block swizzle (nwg % 8 == 0 for both GEMMs)
    constexpr int NBX = N / 256;
    constexpr int NWG = (M_TOT / 256) * NBX;
    constexpr int CPX = NWG / 8;
    int bid = blockIdx.y * NBX + blockIdx.x;
    bid = (bid & 7) * CPX + (bid >> 3);
    const int n0 = (bid % NBX) * 256;
    const int m0 = (bid / NBX) * 256;

    // staging: thread t covers LDS bytes t*16 of each 8KB round (64 rows x 128B).
    // source pre-swizzle: 16B-slot ^= (row & 7)  (involution, matches read XOR)
    const int srow = tid >> 3;                       // 0..63 row-in-round
    const int sseg = (tid & 7) ^ (srow & 7);         // swizzled 16B slot
    const _Float16* gA = A + (size_t)(m0 + srow) * K + sseg * 8;
    const _Float16* gB = B + (size_t)(n0 + srow) * K + sseg * 8;
    const int ldsw = w * 512;                        // wave offset in a round (f16)
    const size_t R1 = (size_t)64 * K, R2 = (size_t)128 * K, R3 = (size_t)192 * K;

    // fragment reads: row*64 + ((ks*4+kq) ^ (row&7))*8 ; row&7 == fr&7 always
    const int xorv = fr & 7;
    const int cA0 = (kq ^ xorv) * 8;         // ks=0 slot (elements)
    const int cA1 = ((kq + 4) ^ xorv) * 8;   // ks=1 slot
    const int aRow = wr * 128 + fr;
    const int bRow = wc * 64 + fr;

    f32x4 acc[8][4];
#pragma unroll
    for (int i = 0; i < 8; i++)
#pragma unroll
        for (int j = 0; j < 4; j++) acc[i][j] = (f32x4){0.f, 0.f, 0.f, 0.f};

    f16x8 bfr[4][2];

    constexpr int NK = K / 64;

    // prologue: stage tile 0 into buf0, drain, one barrier.
    gl16(gB,      sB + ldsw);
    gl16(gB + R1, sB + 4096 + ldsw);
    gl16(gB + R2, sB + 8192 + ldsw);
    gl16(gB + R3, sB + 12288 + ldsw);
    gl16(gA,      sA + ldsw);
    gl16(gA + R1, sA + 4096 + ldsw);
    gl16(gA + R2, sA + 8192 + ldsw);
    gl16(gA + R3, sA + 12288 + ldsw);
    asm volatile("s_waitcnt vmcnt(0)" ::: "memory");
    __builtin_amdgcn_s_barrier();
    asm volatile("" ::: "memory");

    for (int t = 0; t < NK; ++t) {
        const int c = t & 1;
        const _Float16* sAc = sA + c * 16384;
        const _Float16* sBc = sB + c * 16384;
        _Float16* sAn = sA + (c ^ 1) * 16384;
        _Float16* sBn = sB + (c ^ 1) * 16384;
        const bool pref = (t + 1 < NK);

        // issue ALL next-tile stages up front: maximally old at the tile-end
        // drain (~2500cy > HBM latency), and buf^1 is free (its last readers
        // finished before the barrier that ended tile t-1).
        if (pref) {
            const _Float16* gAn = gA + (size_t)(t + 1) * 64;
            const _Float16* gBn = gB + (size_t)(t + 1) * 64;
            gl16(gBn,      sBn + ldsw);
            gl16(gBn + R1, sBn + 4096 + ldsw);
            gl16(gBn + R2, sBn + 8192 + ldsw);
            gl16(gBn + R3, sBn + 12288 + ldsw);
            gl16(gAn,      sAn + ldsw);
            gl16(gAn + R1, sAn + 4096 + ldsw);
            gl16(gAn + R2, sAn + 8192 + ldsw);
            gl16(gAn + R3, sAn + 12288 + ldsw);
        }

        // 4 phases, no intra-tile barriers: waves desync, MFMA || ds_read
        // across waves; compiler pipelines reads(p+1) under MFMA(p) per-wave.
#pragma unroll
        for (int p = 0; p < 4; ++p) {
            f16x8 afr[2][2];
#pragma unroll
            for (int ii = 0; ii < 2; ii++) {
                const _Float16* ra = sAc + (aRow + (2 * p + ii) * 16) * 64;
                afr[ii][0] = *(const f16x8*)(ra + cA0);
                afr[ii][1] = *(const f16x8*)(ra + cA1);
            }
            if (p == 0) {
#pragma unroll
                for (int j = 0; j < 4; j++) {
                    const _Float16* rb = sBc + (bRow + j * 16) * 64;
                    bfr[j][0] = *(const f16x8*)(rb + cA0);
                    bfr[j][1] = *(const f16x8*)(rb + cA1);
                }
            }
            __builtin_amdgcn_s_setprio(1);
#pragma unroll
            for (int ii = 0; ii < 2; ii++)
#pragma unroll
                for (int j = 0; j < 4; j++) {
                    acc[2*p+ii][j] = __builtin_amdgcn_mfma_f32_16x16x32_f16(
                        afr[ii][0], bfr[j][0], acc[2*p+ii][j], 0, 0, 0);
                    acc[2*p+ii][j] = __builtin_amdgcn_mfma_f32_16x16x32_f16(
                        afr[ii][1], bfr[j][1], acc[2*p+ii][j], 0, 0, 0);
                }
            __builtin_amdgcn_s_setprio(0);
        }

        // tile boundary: drain own stages (old loads -> cheap), then the one
        // barrier that makes all waves' stages visible & frees buf c.
        asm volatile("s_waitcnt vmcnt(0)" ::: "memory");
        __builtin_amdgcn_s_barrier();
        asm volatile("" ::: "memory");
    }

    // epilogue (C frag layout: col = lane&15, row = kq*4 + reg)
    const int col0 = n0 + wc * 64 + fr;
    if constexpr (G1) {
        // quantize -> swizzled LDS C-tile (f16 [256][256]) -> coalesced stores.
        // 16B-slot swizzle: slot ^= (row&7) ^ ((row>>3)&1)  (2-way residual only)
        _Float16* Cq = (_Float16*)Cv;
        float bv[4];
#pragma unroll
        for (int j = 0; j < 4; j++) bv[j] = bias[col0 + j * 16];
        const int sub = (fr & 7) * 2;             // byte within 16B slot
        const int slotbase = wc * 8 + (fr >> 3);  // + j*2
        const int rowbase = wr * 128 + kq * 4;    // + i*16 + r
#pragma unroll
        for (int i = 0; i < 8; i++) {
            const int trow0 = rowbase + i * 16;
#pragma unroll
            for (int r = 0; r < 4; r++) {
                const int trow = trow0 + r;
                const int swz = (((kq & 1) * 4 + r)) ^ (kq >> 1);  // == (trow&7)^((trow>>3)&1)
#pragma unroll
                for (int j = 0; j < 4; j++) {
                    float v = fmaxf(acc[i][j][r] + bv[j], 0.0f);
                    _Float16 q = q_e4m3_pos(v);
                    int byte = trow * 512 + (((slotbase + j * 2) ^ swz) << 4) + sub;
                    *(_Float16*)((char*)smem + byte) = q;
                }
            }
        }
        __syncthreads();
#pragma unroll
        for (int cch = 0; cch < 16; cch++) {
            int flat = cch * 512 + tid;          // 16B-chunk index, 8192 total
            int row  = flat >> 5;                // 0..255
            int slot = flat & 31;
            int swz  = (row & 7) ^ ((row >> 3) & 1);
            f16x8 v8 = *(const f16x8*)((char*)smem + row * 512 + ((slot ^ swz) << 4));
            *(f16x8*)(Cq + (size_t)(m0 + row) * N + n0 + slot * 8) = v8;
        }
    } else {
        const int row0 = m0 + wr * 128 + kq * 4;
        float* C = (float*)Cv;
#pragma unroll
        for (int j = 0; j < 4; j++) {
            const float bq = (float)(_Float16)bias[col0 + j * 16];
#pragma unroll
            for (int i = 0; i < 8; i++) {
                size_t base = (size_t)(row0 + i * 16) * N + (col0 + j * 16);
#pragma unroll
                for (int r = 0; r < 4; r++) {
                    float v = acc[i][j][r] + bq;
                    C[base + (size_t)r * N] = (float)(_Float16)v;
                }
            }
        }
    }
}

extern "C" void kernel_launch(void* const* d_in, const int* in_sizes, int n_in,
                              void* d_out, int out_size, void* d_ws, size_t ws_size,
                              hipStream_t stream) {
    const float* x  = (const float*)d_in[0];   // [16384,1024]
    const float* w1 = (const float*)d_in[1];   // [4096,1024]
    const float* b1 = (const float*)d_in[2];   // [4096]
    const float* w2 = (const float*)d_in[3];   // [1024,4096]
    const float* b2 = (const float*)d_in[4];   // [1024]
    float* out = (float*)d_out;

    // workspace layout (bytes):
    // hq  f16 [16384,4096] : 134,217,728
    // xh  f16 [16384,1024] :  33,554,432
    // w1h f16 [4096,1024]  :   8,388,608
    // wq  f16 [1024,4096]  :   8,388,608
    const size_t need = 134217728ull + 33554432ull + 2ull * 8388608ull;
    if (ws_size < need) return;  // fail visibly (output stays zero)

    char* ws = (char*)d_ws;
    _Float16* hq  = (_Float16*)ws;
    _Float16* xh  = (_Float16*)(ws + 134217728ull);
    _Float16* w1h = xh + 16777216;
    _Float16* wq  = w1h + 4194304;

    cvt_f16_kernel<<<16384, 256, 0, stream>>>(x, xh, 4194304);
    cvt_f16_kernel<<<4096, 256, 0, stream>>>(w1, w1h, 1048576);
    quant_e4m3_kernel<<<4096, 256, 0, stream>>>(w2, wq, 1048576);

    // GEMM1: M=16384, N=4096, K=1024 -> grid (16,64) = 1024 wg
    gemm_ffn<D_DIM, H_DIM, true ><<<dim3(H_DIM / 256, M_TOT / 256), 512, 0, stream>>>(xh, w1h, b1, hq);
    // GEMM2: M=16384, N=1024, K=4096 -> grid (4,64) = 256 wg (1 per CU)
    gemm_ffn<H_DIM, D_DIM, false><<<dim3(D_DIM / 256, M_TOT / 256), 512, 0, stream>>>(hq, wq, b2, out);
}